// Round 9
// baseline (297.783 us; speedup 1.0000x reference)
//
#include <hip/hip_runtime.h>

typedef __bf16 bf16;
typedef __attribute__((ext_vector_type(8))) __bf16 bf16x8;
typedef __attribute__((ext_vector_type(4))) float f32x4;

#define B_SZ 2
#define SEQ 2048
#define DM 1024
#define NH 16
#define HD 64
#define DFF 4096
#define NROWS (B_SZ*SEQ)   // 4096

// Q is pre-scaled by 0.125*log2(e) in the QKV epilogue; softmax runs in base-2.
#define QSCALE 0.18033688f   // 0.125 * log2(e)
#define DEFER_THR 11.541561f // 8 * log2(e): P bounded by e^8, bf16-safe

__device__ __forceinline__ f32x4 mfma16(bf16x8 a, bf16x8 b, f32x4 c) {
    return __builtin_amdgcn_mfma_f32_16x16x32_bf16(a, b, c, 0, 0, 0);
}

__device__ __forceinline__ void gload16(const bf16* g, bf16* l) {
    __builtin_amdgcn_global_load_lds(
        (const __attribute__((address_space(1))) void*)g,
        (__attribute__((address_space(3))) void*)l, 16, 0, 0);
}

// ---------------- elementwise kernels ----------------

// all weight conversions in one launch: 16M bf16 elements, 8 per thread
// gate/up interleave (32-feature granularity): wgub row fr: g=fr>>6, r=fr&63,
// feature f = g*32 + (r&31), source = (r&32) ? up : gate.
__global__ __launch_bounds__(256) void convert_all_k(
    const float* __restrict__ wq, const float* __restrict__ wk,
    const float* __restrict__ wv, const float* __restrict__ wo,
    const float* __restrict__ wg, const float* __restrict__ wu,
    const float* __restrict__ wd,
    bf16* __restrict__ wqkvb, bf16* __restrict__ wob,
    bf16* __restrict__ wgub, bf16* __restrict__ wdb) {
    const long M1 = 1l << 20;
    long i = ((long)blockIdx.x * 256 + threadIdx.x) * 8;   // < 16M
    const float* src; bf16* dst; long off;
    if (i < 3 * M1) {                       // fused qkv weight
        int sct = (int)(i >> 20);
        src = sct == 0 ? wq : (sct == 1 ? wk : wv);
        off = i & (M1 - 1); dst = wqkvb + i;
    } else if (i < 4 * M1) {                // wo
        src = wo; off = i - 3 * M1; dst = wob + off;
    } else if (i < 12 * M1) {               // gate/up interleaved (32-granular)
        long j = i - 4 * M1;
        int fr = (int)(j >> 10), c = (int)(j & 1023);
        int g = fr >> 6, r = fr & 63;
        int f = g * 32 + (r & 31);
        src = (r & 32) ? wu : wg; off = (long)f * 1024 + c; dst = wgub + j;
    } else {                                // w_down
        src = wd; off = i - 12 * M1; dst = wdb + off;
    }
    float4 v0 = *(const float4*)(src + off);
    float4 v1 = *(const float4*)(src + off + 4);
    dst[0] = (bf16)v0.x; dst[1] = (bf16)v0.y; dst[2] = (bf16)v0.z; dst[3] = (bf16)v0.w;
    dst[4] = (bf16)v1.x; dst[5] = (bf16)v1.y; dst[6] = (bf16)v1.z; dst[7] = (bf16)v1.w;
}

__global__ __launch_bounds__(256) void rope_table_k(const float* __restrict__ rope,
                                                    float* __restrict__ ct,
                                                    float* __restrict__ st) {
    int i = blockIdx.x * 256 + threadIdx.x;     // 0 .. 2048*32-1
    int sI = i >> 5, d = i & 31;
    float f = rope[sI * 64 + d];
    ct[i] = cosf(f);
    st[i] = sinf(f);
}

// one row per WAVE: 16 f32/lane, wave shuffle reduce, no LDS/barrier.
__global__ __launch_bounds__(256) void rmsnorm_k(const float* __restrict__ x,
                                                 const float* __restrict__ w,
                                                 bf16* __restrict__ o) {
    const int wv = threadIdx.x >> 6, l = threadIdx.x & 63;
    const long row = (long)blockIdx.x * 4 + wv;
    const float4* xr = (const float4*)(x + row * DM);
    float4 v[4];
    float ss = 0.f;
    #pragma unroll
    for (int j = 0; j < 4; ++j) {
        v[j] = xr[l + j * 64];
        ss += v[j].x*v[j].x + v[j].y*v[j].y + v[j].z*v[j].z + v[j].w*v[j].w;
    }
    #pragma unroll
    for (int off = 32; off >= 1; off >>= 1) ss += __shfl_xor(ss, off, 64);
    float scale = 1.f / (sqrtf(ss * (1.f / (float)DM)) + 1e-6f);
    bf16* orow = o + row * DM;
    #pragma unroll
    for (int j = 0; j < 4; ++j) {
        float4 wv4 = ((const float4*)w)[l + j * 64];
        bf16 t[4];
        t[0] = (bf16)(v[j].x * scale * wv4.x);
        t[1] = (bf16)(v[j].y * scale * wv4.y);
        t[2] = (bf16)(v[j].z * scale * wv4.z);
        t[3] = (bf16)(v[j].w * scale * wv4.w);
        *(short4*)(orow + (l + j * 64) * 4) = *(short4*)t;
    }
}

// ------------- 256x256 GEMM, counted-vmcnt half-tile pipeline depth-3, T2 swizzle -------------
// EPI 0: QKV -> q (pre-scaled QSCALE) / k RoPE'd [bh][s][64], v transposed [bh][d][2048]
// EPI 3: gate/up (32-feature interleave) -> silu(g)*u, zero-exchange (same-lane g,u)

template<int EPI>
__global__ __launch_bounds__(512, 2)
void gemm256(const bf16* __restrict__ A, const bf16* __restrict__ W,
             int K, bf16* __restrict__ o1, bf16* __restrict__ o2,
             bf16* __restrict__ o3,
             const float* __restrict__ ct, const float* __restrict__ st) {
    __shared__ __align__(16) char smem[131072];
    bf16* Ah = (bf16*)smem;                 // [ph&3][8192]
    bf16* Bh = (bf16*)(smem + 65536);
    const int tid = threadIdx.x;
    const int wid = tid >> 6, l = tid & 63;
    const int lr = l & 15, lg = l >> 4;
    const int wr = wid >> 2, wcn = wid & 3;         // 2M x 4N
    const int nwg = gridDim.x * gridDim.y;
    const int orig = blockIdx.y * gridDim.x + blockIdx.x;
    const int swz = (orig & 7) * (nwg >> 3) + (orig >> 3);
    const int bx = swz % gridDim.x, by = swz / gridDim.x;
    const long mbase = (long)bx * 256;
    const long nbase = (long)by * 256;

    f32x4 acc[8][4] = {};
    const int nk = K >> 6;
    const int P = nk * 2;

    const int aoff0 = lr * 64 + ((wr * 4 + lg) ^ (lr & 7)) * 8;
    const int boff0 = ((wcn & 1) * 64 + lr) * 64 + (((wcn >> 1) * 4 + lg) ^ (lr & 7)) * 8;

    auto stageHalf = [&](int ph) {
        const int buf = ph & 3, h = ph & 1, kt = ph >> 1;
        bf16* abase = Ah + buf * 8192;
        bf16* bbase = Bh + buf * 8192;
        const long kcol = (long)kt * 64 + h * 32;
        #pragma unroll
        for (int i = 0; i < 2; ++i) {
            int s = i * 512 + tid;           // 0..1023
            int prow = s >> 3, pblk = s & 7;
            int L = pblk ^ (prow & 7);
            long gr = (long)((L >> 2) * 128 + prow);
            long gc = kcol + (L & 3) * 8;
            gload16(&A[(mbase + gr) * K + gc], abase + s * 8);
            gload16(&W[(nbase + gr) * K + gc], bbase + s * 8);
        }
    };

    auto computeHalf = [&](int ph) {
        const int buf = ph & 3;
        const bf16* abase = Ah + buf * 8192;
        const bf16* bbase = Bh + buf * 8192;
        bf16x8 bfr[4];
        #pragma unroll
        for (int ni = 0; ni < 4; ++ni)
            bfr[ni] = *(const bf16x8*)&bbase[ni * 1024 + boff0];
        #pragma unroll
        for (int ms = 0; ms < 2; ++ms) {
            bf16x8 af[4];
            #pragma unroll
            for (int mi = 0; mi < 4; ++mi)
                af[mi] = *(const bf16x8*)&abase[(ms * 4 + mi) * 1024 + aoff0];
            __builtin_amdgcn_s_setprio(1);
            #pragma unroll
            for (int mi = 0; mi < 4; ++mi)
                #pragma unroll
                for (int ni = 0; ni < 4; ++ni)
                    acc[ms * 4 + mi][ni] = mfma16(af[mi], bfr[ni], acc[ms * 4 + mi][ni]);
            __builtin_amdgcn_s_setprio(0);
        }
    };

    stageHalf(0);
    stageHalf(1);
    stageHalf(2);
    for (int p = 0; p < P; ++p) {
        if (p < P - 2)       asm volatile("s_waitcnt vmcnt(8)" ::: "memory");
        else if (p == P - 2) asm volatile("s_waitcnt vmcnt(4)" ::: "memory");
        else                 asm volatile("s_waitcnt vmcnt(0)" ::: "memory");
        __builtin_amdgcn_s_barrier();
        __builtin_amdgcn_sched_barrier(0);
        if (p + 3 < P) stageHalf(p + 3);
        computeHalf(p);
    }

    if (EPI == 0) {
        const long colW = nbase + wcn * 64;
        const int sect = (int)(colW >> 10);        // 0=q 1=k 2=v
        const int hh = (int)((colW >> 6) & 15);
        #pragma unroll
        for (int a = 0; a < 8; ++a) {
            #pragma unroll
            for (int nn = 0; nn < 2; ++nn) {
                const int dd = nn * 16 + lr;       // 0..31
                #pragma unroll
                for (int r = 0; r < 4; ++r) {
                    long row = mbase + wr * 128 + a * 16 + 4 * lg + r;
                    int b = (int)(row >> 11), s = (int)(row & 2047);
                    float v1 = acc[a][nn][r];
                    float v2 = acc[a][nn + 2][r];
                    if (sect < 2) {
                        if (sect == 0) { v1 *= QSCALE; v2 *= QSCALE; }   // pre-scale Q
                        float c = ct[s * 32 + dd], sn = st[s * 32 + dd];
                        bf16* dst = (sect == 0) ? o1 : o2;
                        long pth = (((long)(b * NH + hh) * SEQ + s) << 6) + dd;
                        dst[pth]      = (bf16)(v1 * c - v2 * sn);
                        dst[pth + 32] = (bf16)(v2 * c + v1 * sn);
                    } else {
                        long pth = ((long)(b * NH + hh) * HD + dd) * SEQ + s;
                        o3[pth]            = (bf16)v1;
                        o3[pth + 32 * SEQ] = (bf16)v2;
                    }
                }
            }
        }
    }

    if (EPI == 3) {
        const int fb = (int)(nbase + wcn * 64) >> 1;
        #pragma unroll
        for (int a = 0; a < 8; ++a)
            #pragma unroll
            for (int ni = 0; ni < 2; ++ni)
                #pragma unroll
                for (int r = 0; r < 4; ++r) {
                    long row = mbase + wr * 128 + a * 16 + 4 * lg + r;
                    float g = acc[a][ni][r];
                    float u = acc[a][ni + 2][r];
                    float sg = g / (1.f + __expf(-g));
                    o1[row * 4096 + fb + ni * 16 + lr] = (bf16)(sg * u);
                }
    }
}

// ------- 64x128 GEMM, 3-buffer counted-vmcnt (BK=64 phases), T2 swizzle, f32 resid -------
// of[M,N] = resid[M,N] + A[M,K] @ W[N,K]^T. 512 thr = 8 waves (2M x 4N), wave 32x32.
// LDS 72 KB -> 2 blocks/CU (proven R5 config; 64x256 @1 block/CU regressed in R6).

__global__ __launch_bounds__(512, 4)
void gemm64x128(const bf16* __restrict__ A, const bf16* __restrict__ W,
                int K, int N, const float* __restrict__ resid, float* __restrict__ of) {
    __shared__ bf16 As[3][64 * 64];
    __shared__ bf16 Bs[3][128 * 64];
    const int tid = threadIdx.x;
    const int wid = tid >> 6, l = tid & 63;
    const int lr = l & 15, lg = l >> 4;
    const int wr = wid >> 2, wcn = wid & 3;       // 2M x 4N
    const long mbase = (long)blockIdx.x * 64;
    const long nbase = (long)blockIdx.y * 128;

    f32x4 acc[2][2] = {};
    const int nk = K >> 6;

    auto stage = [&](int b, int kt) {
        {
            int s = tid;                           // A: 512 slots, swizzled source
            int row = s >> 3, pblk = s & 7;
            int L = pblk ^ (row & 7);
            gload16(&A[(mbase + row) * K + kt * 64 + L * 8], &As[b][s * 8]);
        }
        #pragma unroll
        for (int i = 0; i < 2; ++i) {
            int s = i * 512 + tid;                 // B: 1024 slots
            int row = s >> 3, pblk = s & 7;
            int L = pblk ^ (row & 7);
            gload16(&W[(nbase + row) * K + kt * 64 + L * 8], &Bs[b][s * 8]);
        }
    };
    auto compute = [&](int b) {
        #pragma unroll
        for (int kk = 0; kk < 2; ++kk) {
            bf16x8 af[2], bfr[2];
            #pragma unroll
            for (int mi = 0; mi < 2; ++mi) {
                int row = wr * 32 + mi * 16 + lr;
                af[mi] = *(const bf16x8*)&As[b][row * 64 + ((kk * 4 + lg) ^ (lr & 7)) * 8];
            }
            #pragma unroll
            for (int ni = 0; ni < 2; ++ni) {
                int row = wcn * 32 + ni * 16 + lr;
                bfr[ni] = *(const bf16x8*)&Bs[b][row * 64 + ((kk * 4 + lg) ^ (lr & 7)) * 8];
            }
            __builtin_amdgcn_s_setprio(1);
            #pragma unroll
            for (int mi = 0; mi < 2; ++mi)
                #pragma unroll
                for (int ni = 0; ni < 2; ++ni)
                    acc[mi][ni] = mfma16(af[mi], bfr[ni], acc[mi][ni]);
            __builtin_amdgcn_s_setprio(0);
        }
    };

    stage(0, 0);
    stage(1, 1);
    for (int kt = 0; kt < nk; ++kt) {
        if (kt < nk - 1) asm volatile("s_waitcnt vmcnt(3)" ::: "memory");
        else             asm volatile("s_waitcnt vmcnt(0)" ::: "memory");
        __builtin_amdgcn_s_barrier();
        __builtin_amdgcn_sched_barrier(0);
        if (kt + 2 < nk) stage((kt + 2) % 3, kt + 2);
        compute(kt % 3);
    }

    #pragma unroll
    for (int mi = 0; mi < 2; ++mi)
        #pragma unroll
        for (int ni = 0; ni < 2; ++ni)
            #pragma unroll
            for (int r = 0; r < 4; ++r) {
                long row = mbase + wr * 32 + mi * 16 + 4 * lg + r;
                long col = nbase + wcn * 32 + ni * 16 + lr;
                of[row * N + col] = resid[row * N + col] + acc[mi][ni][r];
            }
}

// ---------------- causal flash attention (paired q-tiles, defer-max, base-2 softmax) ----------------
// Q pre-scaled by QSCALE in QKV epilogue; P-lds stride 72 (16B-aligned -> b128 reads).

__device__ __forceinline__ void attn_tile(
    int tb, int qw, bool diag,
    const bf16x8& qf0, const bf16x8& qf1,
    const bf16* Kl, const bf16* Vl, bf16* Plw,
    int lr, int lg, f32x4* oacc, float* mr, f32x4& lacc)
{
    f32x4 s[4];
    __builtin_amdgcn_s_setprio(1);
    #pragma unroll
    for (int tf = 0; tf < 4; ++tf) {
        f32x4 z = {0.f, 0.f, 0.f, 0.f};
        bf16x8 k0 = *(const bf16x8*)&Kl[(tf * 16 + lr) * 64 + ((0 + lg) ^ (lr & 7)) * 8];
        bf16x8 k1 = *(const bf16x8*)&Kl[(tf * 16 + lr) * 64 + ((4 + lg) ^ (lr & 7)) * 8];
        z = mfma16(qf0, k0, z);
        z = mfma16(qf1, k1, z);
        s[tf] = z;
    }
    __builtin_amdgcn_s_setprio(0);

    float pv[4][4];
    float pmax[4] = {-1e30f, -1e30f, -1e30f, -1e30f};
    #pragma unroll
    for (int tf = 0; tf < 4; ++tf) {
        int t = tb + tf * 16 + lr;
        #pragma unroll
        for (int r = 0; r < 4; ++r) {
            float sv = s[tf][r];
            if (diag && t > qw + 4 * lg + r) sv = -1e30f;
            pv[tf][r] = sv;
            pmax[r] = fmaxf(pmax[r], sv);
        }
    }
    #pragma unroll
    for (int r = 0; r < 4; ++r) {
        pmax[r] = fmaxf(pmax[r], __shfl_xor(pmax[r], 8, 64));
        pmax[r] = fmaxf(pmax[r], __shfl_xor(pmax[r], 4, 64));
        pmax[r] = fmaxf(pmax[r], __shfl_xor(pmax[r], 2, 64));
        pmax[r] = fmaxf(pmax[r], __shfl_xor(pmax[r], 1, 64));
    }
    // T13 defer-max (base-2 units): skip rescale while exp2 stays bounded by e^8
    bool within = (pmax[0] <= mr[0] + DEFER_THR) && (pmax[1] <= mr[1] + DEFER_THR) &&
                  (pmax[2] <= mr[2] + DEFER_THR) && (pmax[3] <= mr[3] + DEFER_THR);
    if (!__all(within)) {
        float alpha[4];
        #pragma unroll
        for (int r = 0; r < 4; ++r) {
            float mn = fmaxf(mr[r], pmax[r]);
            alpha[r] = exp2f(mr[r] - mn);
            mr[r] = mn;
        }
        #pragma unroll
        for (int r = 0; r < 4; ++r) lacc[r] *= alpha[r];
        #pragma unroll
        for (int df = 0; df < 4; ++df) {
            f32x4 t4 = oacc[df];
            t4[0] *= alpha[0]; t4[1] *= alpha[1];
            t4[2] *= alpha[2]; t4[3] *= alpha[3];
            oacc[df] = t4;
        }
    }
    #pragma unroll
    for (int tf = 0; tf < 4; ++tf)
        #pragma unroll
        for (int r = 0; r < 4; ++r)
            Plw[(4 * lg + r) * 72 + tf * 16 + lr] = (bf16)exp2f(pv[tf][r] - mr[r]);

    // P fragments: stride-72 rows are 16B-aligned -> two b128 reads (was 16 b16)
    bf16x8 pa0 = *(const bf16x8*)&Plw[lr * 72 + lg * 8];
    bf16x8 pa1 = *(const bf16x8*)&Plw[lr * 72 + 32 + lg * 8];
    bf16x8 ones;
    #pragma unroll
    for (int j = 0; j < 8; ++j) ones[j] = (bf16)1.0f;
    __builtin_amdgcn_s_setprio(1);
    lacc = mfma16(pa0, ones, lacc);
    lacc = mfma16(pa1, ones, lacc);
    #pragma unroll
    for (int df = 0; df < 4; ++df) {
        bf16x8 v0 = *(const bf16x8*)&Vl[(df * 16 + lr) * 64 + ((0 + lg) ^ (lr & 7)) * 8];
        bf16x8 v1 = *(const bf16x8*)&Vl[(df * 16 + lr) * 64 + ((4 + lg) ^ (lr & 7)) * 8];
        oacc[df] = mfma16(pa0, v0, oacc[df]);
        oacc[df] = mfma16(pa1, v1, oacc[df]);
    }
    __builtin_amdgcn_s_setprio(0);
}

__global__ __launch_bounds__(256)
void attn_fwd(const bf16* __restrict__ q, const bf16* __restrict__ k,
              const bf16* __restrict__ vt, bf16* __restrict__ o) {
    __shared__ bf16 Kl[2][64 * 64];
    __shared__ bf16 Vl[2][64 * 64];
    __shared__ bf16 Pl[4][16 * 72];
    const int tid = threadIdx.x, wid = tid >> 6, l = tid & 63;
    const int lr = l & 15, lg = l >> 4;
    const int qtA = blockIdx.x;           // 0..15
    const int qtB = 31 - qtA;             // 31..16
    const int bh = blockIdx.y;
    const long kbase = (long)bh * SEQ * HD;
    const long vbase = (long)bh * HD * SEQ;
    const int qwA = qtA * 64 + wid * 16;
    const int qwB = qtB * 64 + wid * 16;

    bf16x8 qA0, qA1, qB0, qB1;
    {
        const bf16* qp = q + kbase + (long)(qwA + lr) * HD + lg * 8;
        qA0 = *(const bf16x8*)qp; qA1 = *(const bf16x8*)(qp + 32);
        const bf16* qp2 = q + kbase + (long)(qwB + lr) * HD + lg * 8;
        qB0 = *(const bf16x8*)qp2; qB1 = *(const bf16x8*)(qp2 + 32);
    }
    f32x4 oA[4] = {}, oB[4] = {};
    f32x4 lA = {0.f, 0.f, 0.f, 0.f}, lB = {0.f, 0.f, 0.f, 0.f};
    float mA[4] = {-1e30f, -1e30f, -1e30f, -1e30f};
    float mB[4] = {-1e30f, -1e30f, -1e30f, -1e30f};

    auto stageKV = [&](int b, int tb) {
        #pragma unroll
        for (int i = 0; i < 4; ++i) {
            int slot = i * 256 + tid;
            int row = (slot >> 3) & 63;
            int bs = (slot & 7) ^ (row & 7);
            if (slot < 512)
                gload16(&k[kbase + (long)(tb + row) * HD + bs * 8], &Kl[b][slot * 8]);
            else
                gload16(&vt[vbase + (long)row * SEQ + tb + bs * 8], &Vl[b][(slot - 512) * 8]);
        }
    };

    const int nt = qtB + 1;
    stageKV(0, 0);
    __syncthreads();
    int cur = 0;
    for (int tb_i = 0; tb_i < nt; ++tb_i) {
        const int tb = tb_i * 64;
        if (tb_i + 1 < nt) stageKV(cur ^ 1, tb + 64);
        if (tb_i <= qtA)
            attn_tile(tb, qwA, tb_i == qtA, qA0, qA1, Kl[cur], Vl[cur], Pl[wid], lr, lg, oA, mA, lA);
        attn_tile(tb, qwB, tb_i == qtB, qB0, qB1, Kl[cur], Vl[cur], Pl[wid], lr, lg, oB, mB, lB);
        __syncthreads();
        cur ^= 1;
    }

    const int b = bh >> 4, h = bh & 15;
    #pragma unroll
    for (int df = 0; df < 4; ++df) {
        #pragma unroll
        for (int r = 0; r < 4; ++r) {
            int sA = qwA + 4 * lg + r;
            int sB = qwB + 4 * lg + r;
            o[((long)(b * SEQ + sA) * DM) + h * HD + df * 16 + lr] = (bf16)(oA[df][r] / lA[r]);
            o[((long)(b * SEQ + sB) * DM) + h * HD + df * 16 + lr] = (bf16)(oB[df][r] / lB[r]);
        }
    }
}

// ---------------- launch ----------------

extern "C" void kernel_launch(void* const* d_in, const int* in_sizes, int n_in,
                              void* d_out, int out_size, void* d_ws, size_t ws_size,
                              hipStream_t stream) {
    (void)in_sizes; (void)n_in; (void)out_size; (void)ws_size;
    const float* x    = (const float*)d_in[0];
    const float* rope = (const float*)d_in[1];
    const float* wq   = (const float*)d_in[2];
    const float* wk   = (const float*)d_in[3];
    const float* wv   = (const float*)d_in[4];
    const float* wo   = (const float*)d_in[5];
    const float* wg   = (const float*)d_in[6];
    const float* wu   = (const float*)d_in[7];
    const float* wd   = (const float*)d_in[8];
    const float* n1w  = (const float*)d_in[9];
    const float* n2w  = (const float*)d_in[10];
    float* out = (float*)d_out;

    char* ws = (char*)d_ws;
    const size_t MB = 1u << 20;
    bf16* wqkvb = (bf16*)(ws + 0 * MB);    // [3072][1024]  6 MB
    bf16* wob   = (bf16*)(ws + 6 * MB);    // [1024][1024]  2 MB
    bf16* wgub  = (bf16*)(ws + 8 * MB);    // [8192][1024] 16 MB (gate/up 32-interleave)
    bf16* wdb   = (bf16*)(ws + 24 * MB);   // [1024][4096]  8 MB
    bf16* hb    = (bf16*)(ws + 32 * MB);   //  8 MB
    bf16* qb_   = (bf16*)(ws + 40 * MB);   // 16 MB
    bf16* kb_   = (bf16*)(ws + 56 * MB);   // 16 MB
    bf16* vtb   = (bf16*)(ws + 72 * MB);   // 16 MB
    bf16* attnb = (bf16*)(ws + 88 * MB);   // 16 MB
    float* x2   = (float*)(ws + 40 * MB);  // 16 MB (aliases qb_, dead after attn)
    bf16* midb  = (bf16*)(ws + 56 * MB);   // 32 MB (aliases kb_+vtb, dead after attn)
    float* ctab = (float*)(ws + 104 * MB);
    float* stab = (float*)(ws + 104 * MB + (1u << 18));

    // all weights -> bf16 in one launch
    convert_all_k<<<8192, 256, 0, stream>>>(wq, wk, wv, wo, wg, wu, wd,
                                            wqkvb, wob, wgub, wdb);
    rope_table_k<<<256, 256, 0, stream>>>(rope, ctab, stab);

    // norm1 -> h
    rmsnorm_k<<<NROWS / 4, 256, 0, stream>>>(x, n1w, hb);

    // fused QKV (+RoPE on q/k, q pre-scaled, V transposed)
    gemm256<0><<<dim3(16, 12), 512, 0, stream>>>(hb, wqkvb, DM, qb_, kb_, vtb, ctab, stab);

    // attention
    attn_fwd<<<dim3(16, 32), 256, 0, stream>>>(qb_, kb_, vtb, attnb);

    // WO + residual -> x2 (f32)
    gemm64x128<<<dim3(64, 8), 512, 0, stream>>>(attnb, wob, DM, DM, x, x2);

    // norm2 -> h
    rmsnorm_k<<<NROWS / 4, 256, 0, stream>>>(x2, n2w, hb);

    // fused gate+up+silu -> midb
    gemm256<3><<<dim3(16, 32), 512, 0, stream>>>(hb, wgub, DM, midb, nullptr, nullptr, nullptr, nullptr);

    // down + residual -> out
    gemm64x128<<<dim3(64, 8), 512, 0, stream>>>(midb, wdb, DFF, DM, x2, out);
}

// Round 10
// 284.994 us; speedup vs baseline: 1.0449x; 1.0449x over previous
//
#include <hip/hip_runtime.h>

typedef __bf16 bf16;
typedef __attribute__((ext_vector_type(8))) __bf16 bf16x8;
typedef __attribute__((ext_vector_type(4))) float f32x4;

#define B_SZ 2
#define SEQ 2048
#define DM 1024
#define NH 16
#define HD 64
#define DFF 4096
#define NROWS (B_SZ*SEQ)   // 4096

// Q is pre-scaled by 0.125*log2(e) in the QKV epilogue; softmax runs in base-2.
#define QSCALE 0.18033688f   // 0.125 * log2(e)
#define DEFER_THR 11.541561f // 8 * log2(e): P bounded by e^8, bf16-safe

__device__ __forceinline__ f32x4 mfma16(bf16x8 a, bf16x8 b, f32x4 c) {
    return __builtin_amdgcn_mfma_f32_16x16x32_bf16(a, b, c, 0, 0, 0);
}

__device__ __forceinline__ void gload16(const bf16* g, bf16* l) {
    __builtin_amdgcn_global_load_lds(
        (const __attribute__((address_space(1))) void*)g,
        (__attribute__((address_space(3))) void*)l, 16, 0, 0);
}

// ---------------- elementwise kernels ----------------

// all weight conversions in one launch: 16M bf16 elements, 8 per thread
// gate/up interleave (32-feature granularity): wgub row fr: g=fr>>6, r=fr&63,
// feature f = g*32 + (r&31), source = (r&32) ? up : gate.
__global__ __launch_bounds__(256) void convert_all_k(
    const float* __restrict__ wq, const float* __restrict__ wk,
    const float* __restrict__ wv, const float* __restrict__ wo,
    const float* __restrict__ wg, const float* __restrict__ wu,
    const float* __restrict__ wd,
    bf16* __restrict__ wqkvb, bf16* __restrict__ wob,
    bf16* __restrict__ wgub, bf16* __restrict__ wdb) {
    const long M1 = 1l << 20;
    long i = ((long)blockIdx.x * 256 + threadIdx.x) * 8;   // < 16M
    const float* src; bf16* dst; long off;
    if (i < 3 * M1) {                       // fused qkv weight
        int sct = (int)(i >> 20);
        src = sct == 0 ? wq : (sct == 1 ? wk : wv);
        off = i & (M1 - 1); dst = wqkvb + i;
    } else if (i < 4 * M1) {                // wo
        src = wo; off = i - 3 * M1; dst = wob + off;
    } else if (i < 12 * M1) {               // gate/up interleaved (32-granular)
        long j = i - 4 * M1;
        int fr = (int)(j >> 10), c = (int)(j & 1023);
        int g = fr >> 6, r = fr & 63;
        int f = g * 32 + (r & 31);
        src = (r & 32) ? wu : wg; off = (long)f * 1024 + c; dst = wgub + j;
    } else {                                // w_down
        src = wd; off = i - 12 * M1; dst = wdb + off;
    }
    float4 v0 = *(const float4*)(src + off);
    float4 v1 = *(const float4*)(src + off + 4);
    dst[0] = (bf16)v0.x; dst[1] = (bf16)v0.y; dst[2] = (bf16)v0.z; dst[3] = (bf16)v0.w;
    dst[4] = (bf16)v1.x; dst[5] = (bf16)v1.y; dst[6] = (bf16)v1.z; dst[7] = (bf16)v1.w;
}

__global__ __launch_bounds__(256) void rope_table_k(const float* __restrict__ rope,
                                                    float* __restrict__ ct,
                                                    float* __restrict__ st) {
    int i = blockIdx.x * 256 + threadIdx.x;     // 0 .. 2048*32-1
    int sI = i >> 5, d = i & 31;
    float f = rope[sI * 64 + d];
    ct[i] = cosf(f);
    st[i] = sinf(f);
}

// one row per WAVE: 16 f32/lane, wave shuffle reduce, no LDS/barrier.
__global__ __launch_bounds__(256) void rmsnorm_k(const float* __restrict__ x,
                                                 const float* __restrict__ w,
                                                 bf16* __restrict__ o) {
    const int wv = threadIdx.x >> 6, l = threadIdx.x & 63;
    const long row = (long)blockIdx.x * 4 + wv;
    const float4* xr = (const float4*)(x + row * DM);
    float4 v[4];
    float ss = 0.f;
    #pragma unroll
    for (int j = 0; j < 4; ++j) {
        v[j] = xr[l + j * 64];
        ss += v[j].x*v[j].x + v[j].y*v[j].y + v[j].z*v[j].z + v[j].w*v[j].w;
    }
    #pragma unroll
    for (int off = 32; off >= 1; off >>= 1) ss += __shfl_xor(ss, off, 64);
    float scale = 1.f / (sqrtf(ss * (1.f / (float)DM)) + 1e-6f);
    bf16* orow = o + row * DM;
    #pragma unroll
    for (int j = 0; j < 4; ++j) {
        float4 wv4 = ((const float4*)w)[l + j * 64];
        bf16 t[4];
        t[0] = (bf16)(v[j].x * scale * wv4.x);
        t[1] = (bf16)(v[j].y * scale * wv4.y);
        t[2] = (bf16)(v[j].z * scale * wv4.z);
        t[3] = (bf16)(v[j].w * scale * wv4.w);
        *(short4*)(orow + (l + j * 64) * 4) = *(short4*)t;
    }
}

// ------------- 256x256 GEMM, counted-vmcnt half-tile pipeline depth-3, T2 swizzle -------------
// EPI 0: QKV -> q (pre-scaled QSCALE) / k RoPE'd [bh][s][64], v transposed [bh][d][2048]
// EPI 3: gate/up (32-feature interleave) -> silu(g)*u, zero-exchange (same-lane g,u)

template<int EPI>
__global__ __launch_bounds__(512, 2)
void gemm256(const bf16* __restrict__ A, const bf16* __restrict__ W,
             int K, bf16* __restrict__ o1, bf16* __restrict__ o2,
             bf16* __restrict__ o3,
             const float* __restrict__ ct, const float* __restrict__ st) {
    __shared__ __align__(16) char smem[131072];
    bf16* Ah = (bf16*)smem;                 // [ph&3][8192]
    bf16* Bh = (bf16*)(smem + 65536);
    const int tid = threadIdx.x;
    const int wid = tid >> 6, l = tid & 63;
    const int lr = l & 15, lg = l >> 4;
    const int wr = wid >> 2, wcn = wid & 3;         // 2M x 4N
    const int nwg = gridDim.x * gridDim.y;
    const int orig = blockIdx.y * gridDim.x + blockIdx.x;
    const int swz = (orig & 7) * (nwg >> 3) + (orig >> 3);
    const int bx = swz % gridDim.x, by = swz / gridDim.x;
    const long mbase = (long)bx * 256;
    const long nbase = (long)by * 256;

    f32x4 acc[8][4] = {};
    const int nk = K >> 6;
    const int P = nk * 2;

    const int aoff0 = lr * 64 + ((wr * 4 + lg) ^ (lr & 7)) * 8;
    const int boff0 = ((wcn & 1) * 64 + lr) * 64 + (((wcn >> 1) * 4 + lg) ^ (lr & 7)) * 8;

    auto stageHalf = [&](int ph) {
        const int buf = ph & 3, h = ph & 1, kt = ph >> 1;
        bf16* abase = Ah + buf * 8192;
        bf16* bbase = Bh + buf * 8192;
        const long kcol = (long)kt * 64 + h * 32;
        #pragma unroll
        for (int i = 0; i < 2; ++i) {
            int s = i * 512 + tid;           // 0..1023
            int prow = s >> 3, pblk = s & 7;
            int L = pblk ^ (prow & 7);
            long gr = (long)((L >> 2) * 128 + prow);
            long gc = kcol + (L & 3) * 8;
            gload16(&A[(mbase + gr) * K + gc], abase + s * 8);
            gload16(&W[(nbase + gr) * K + gc], bbase + s * 8);
        }
    };

    auto computeHalf = [&](int ph) {
        const int buf = ph & 3;
        const bf16* abase = Ah + buf * 8192;
        const bf16* bbase = Bh + buf * 8192;
        bf16x8 bfr[4];
        #pragma unroll
        for (int ni = 0; ni < 4; ++ni)
            bfr[ni] = *(const bf16x8*)&bbase[ni * 1024 + boff0];
        #pragma unroll
        for (int ms = 0; ms < 2; ++ms) {
            bf16x8 af[4];
            #pragma unroll
            for (int mi = 0; mi < 4; ++mi)
                af[mi] = *(const bf16x8*)&abase[(ms * 4 + mi) * 1024 + aoff0];
            __builtin_amdgcn_s_setprio(1);
            #pragma unroll
            for (int mi = 0; mi < 4; ++mi)
                #pragma unroll
                for (int ni = 0; ni < 4; ++ni)
                    acc[ms * 4 + mi][ni] = mfma16(af[mi], bfr[ni], acc[ms * 4 + mi][ni]);
            __builtin_amdgcn_s_setprio(0);
        }
    };

    stageHalf(0);
    stageHalf(1);
    stageHalf(2);
    for (int p = 0; p < P; ++p) {
        if (p < P - 2)       asm volatile("s_waitcnt vmcnt(8)" ::: "memory");
        else if (p == P - 2) asm volatile("s_waitcnt vmcnt(4)" ::: "memory");
        else                 asm volatile("s_waitcnt vmcnt(0)" ::: "memory");
        __builtin_amdgcn_s_barrier();
        __builtin_amdgcn_sched_barrier(0);
        if (p + 3 < P) stageHalf(p + 3);
        computeHalf(p);
    }

    if (EPI == 0) {
        const long colW = nbase + wcn * 64;
        const int sect = (int)(colW >> 10);        // 0=q 1=k 2=v
        const int hh = (int)((colW >> 6) & 15);
        #pragma unroll
        for (int a = 0; a < 8; ++a) {
            #pragma unroll
            for (int nn = 0; nn < 2; ++nn) {
                const int dd = nn * 16 + lr;       // 0..31
                #pragma unroll
                for (int r = 0; r < 4; ++r) {
                    long row = mbase + wr * 128 + a * 16 + 4 * lg + r;
                    int b = (int)(row >> 11), s = (int)(row & 2047);
                    float v1 = acc[a][nn][r];
                    float v2 = acc[a][nn + 2][r];
                    if (sect < 2) {
                        if (sect == 0) { v1 *= QSCALE; v2 *= QSCALE; }   // pre-scale Q
                        float c = ct[s * 32 + dd], sn = st[s * 32 + dd];
                        bf16* dst = (sect == 0) ? o1 : o2;
                        long pth = (((long)(b * NH + hh) * SEQ + s) << 6) + dd;
                        dst[pth]      = (bf16)(v1 * c - v2 * sn);
                        dst[pth + 32] = (bf16)(v2 * c + v1 * sn);
                    } else {
                        long pth = ((long)(b * NH + hh) * HD + dd) * SEQ + s;
                        o3[pth]            = (bf16)v1;
                        o3[pth + 32 * SEQ] = (bf16)v2;
                    }
                }
            }
        }
    }

    if (EPI == 3) {
        const int fb = (int)(nbase + wcn * 64) >> 1;
        #pragma unroll
        for (int a = 0; a < 8; ++a)
            #pragma unroll
            for (int ni = 0; ni < 2; ++ni)
                #pragma unroll
                for (int r = 0; r < 4; ++r) {
                    long row = mbase + wr * 128 + a * 16 + 4 * lg + r;
                    float g = acc[a][ni][r];
                    float u = acc[a][ni + 2][r];
                    float sg = g / (1.f + __expf(-g));
                    o1[row * 4096 + fb + ni * 16 + lr] = (bf16)(sg * u);
                }
    }
}

// ------- 64x128 GEMM, 3-buffer counted-vmcnt (BK=64 phases), T2 swizzle, f32 resid -------
// of[M,N] = resid[M,N] + A[M,K] @ W[N,K]^T. 512 thr = 8 waves (2M x 4N), wave 32x32.
// LDS 72 KB -> 2 blocks/CU (proven R5 config; 64x256 @1 block/CU regressed in R6).

__global__ __launch_bounds__(512, 4)
void gemm64x128(const bf16* __restrict__ A, const bf16* __restrict__ W,
                int K, int N, const float* __restrict__ resid, float* __restrict__ of) {
    __shared__ bf16 As[3][64 * 64];
    __shared__ bf16 Bs[3][128 * 64];
    const int tid = threadIdx.x;
    const int wid = tid >> 6, l = tid & 63;
    const int lr = l & 15, lg = l >> 4;
    const int wr = wid >> 2, wcn = wid & 3;       // 2M x 4N
    const long mbase = (long)blockIdx.x * 64;
    const long nbase = (long)blockIdx.y * 128;

    f32x4 acc[2][2] = {};
    const int nk = K >> 6;

    auto stage = [&](int b, int kt) {
        {
            int s = tid;                           // A: 512 slots, swizzled source
            int row = s >> 3, pblk = s & 7;
            int L = pblk ^ (row & 7);
            gload16(&A[(mbase + row) * K + kt * 64 + L * 8], &As[b][s * 8]);
        }
        #pragma unroll
        for (int i = 0; i < 2; ++i) {
            int s = i * 512 + tid;                 // B: 1024 slots
            int row = s >> 3, pblk = s & 7;
            int L = pblk ^ (row & 7);
            gload16(&W[(nbase + row) * K + kt * 64 + L * 8], &Bs[b][s * 8]);
        }
    };
    auto compute = [&](int b) {
        #pragma unroll
        for (int kk = 0; kk < 2; ++kk) {
            bf16x8 af[2], bfr[2];
            #pragma unroll
            for (int mi = 0; mi < 2; ++mi) {
                int row = wr * 32 + mi * 16 + lr;
                af[mi] = *(const bf16x8*)&As[b][row * 64 + ((kk * 4 + lg) ^ (lr & 7)) * 8];
            }
            #pragma unroll
            for (int ni = 0; ni < 2; ++ni) {
                int row = wcn * 32 + ni * 16 + lr;
                bfr[ni] = *(const bf16x8*)&Bs[b][row * 64 + ((kk * 4 + lg) ^ (lr & 7)) * 8];
            }
            __builtin_amdgcn_s_setprio(1);
            #pragma unroll
            for (int mi = 0; mi < 2; ++mi)
                #pragma unroll
                for (int ni = 0; ni < 2; ++ni)
                    acc[mi][ni] = mfma16(af[mi], bfr[ni], acc[mi][ni]);
            __builtin_amdgcn_s_setprio(0);
        }
    };

    stage(0, 0);
    stage(1, 1);
    for (int kt = 0; kt < nk; ++kt) {
        if (kt < nk - 1) asm volatile("s_waitcnt vmcnt(3)" ::: "memory");
        else             asm volatile("s_waitcnt vmcnt(0)" ::: "memory");
        __builtin_amdgcn_s_barrier();
        __builtin_amdgcn_sched_barrier(0);
        if (kt + 2 < nk) stage((kt + 2) % 3, kt + 2);
        compute(kt % 3);
    }

    #pragma unroll
    for (int mi = 0; mi < 2; ++mi)
        #pragma unroll
        for (int ni = 0; ni < 2; ++ni)
            #pragma unroll
            for (int r = 0; r < 4; ++r) {
                long row = mbase + wr * 32 + mi * 16 + 4 * lg + r;
                long col = nbase + wcn * 32 + ni * 16 + lr;
                of[row * N + col] = resid[row * N + col] + acc[mi][ni][r];
            }
}

// ---------------- causal flash attention (paired q-tiles, lane-local defer-max) ----------------
// Q pre-scaled by QSCALE; base-2 softmax. Common path has NO cross-lane reduce:
// __all(lane_local_max <= mr+THR) <=> full_row_max <= mr+THR (identical predicate,
// distributed). Full 16-shuffle reduce + rescale only on the rare failure branch.

__device__ __forceinline__ void attn_tile(
    int tb, int qw, bool diag,
    const bf16x8& qf0, const bf16x8& qf1,
    const bf16* Kl, const bf16* Vl, bf16* Plw,
    int lr, int lg, f32x4* oacc, float* mr, f32x4& lacc)
{
    f32x4 s[4];
    __builtin_amdgcn_s_setprio(1);
    #pragma unroll
    for (int tf = 0; tf < 4; ++tf) {
        f32x4 z = {0.f, 0.f, 0.f, 0.f};
        bf16x8 k0 = *(const bf16x8*)&Kl[(tf * 16 + lr) * 64 + ((0 + lg) ^ (lr & 7)) * 8];
        bf16x8 k1 = *(const bf16x8*)&Kl[(tf * 16 + lr) * 64 + ((4 + lg) ^ (lr & 7)) * 8];
        z = mfma16(qf0, k0, z);
        z = mfma16(qf1, k1, z);
        s[tf] = z;
    }
    __builtin_amdgcn_s_setprio(0);

    float pv[4][4];
    float pml[4];   // lane-local per-row max (over this lane's 4 t-values per row)
    #pragma unroll
    for (int r = 0; r < 4; ++r) pml[r] = -1e30f;
    #pragma unroll
    for (int tf = 0; tf < 4; ++tf) {
        int t = tb + tf * 16 + lr;
        #pragma unroll
        for (int r = 0; r < 4; ++r) {
            float sv = s[tf][r];
            if (diag && t > qw + 4 * lg + r) sv = -1e30f;
            pv[tf][r] = sv;
            pml[r] = fmaxf(pml[r], sv);
        }
    }
    // lane-local defer check: no shuffles in the common path
    bool ok = (pml[0] <= mr[0] + DEFER_THR) && (pml[1] <= mr[1] + DEFER_THR) &&
              (pml[2] <= mr[2] + DEFER_THR) && (pml[3] <= mr[3] + DEFER_THR);
    if (!__all(ok)) {
        // rare path: full per-row max reduce + rescale
        float pmax[4];
        #pragma unroll
        for (int r = 0; r < 4; ++r) {
            pmax[r] = pml[r];
            pmax[r] = fmaxf(pmax[r], __shfl_xor(pmax[r], 8, 64));
            pmax[r] = fmaxf(pmax[r], __shfl_xor(pmax[r], 4, 64));
            pmax[r] = fmaxf(pmax[r], __shfl_xor(pmax[r], 2, 64));
            pmax[r] = fmaxf(pmax[r], __shfl_xor(pmax[r], 1, 64));
        }
        float alpha[4];
        #pragma unroll
        for (int r = 0; r < 4; ++r) {
            float mn = fmaxf(mr[r], pmax[r]);
            alpha[r] = exp2f(mr[r] - mn);
            mr[r] = mn;
        }
        #pragma unroll
        for (int r = 0; r < 4; ++r) lacc[r] *= alpha[r];
        #pragma unroll
        for (int df = 0; df < 4; ++df) {
            f32x4 t4 = oacc[df];
            t4[0] *= alpha[0]; t4[1] *= alpha[1];
            t4[2] *= alpha[2]; t4[3] *= alpha[3];
            oacc[df] = t4;
        }
    }
    #pragma unroll
    for (int tf = 0; tf < 4; ++tf)
        #pragma unroll
        for (int r = 0; r < 4; ++r)
            Plw[(4 * lg + r) * 72 + tf * 16 + lr] = (bf16)exp2f(pv[tf][r] - mr[r]);

    // P fragments: stride-72 rows are 16B-aligned -> two b128 reads
    bf16x8 pa0 = *(const bf16x8*)&Plw[lr * 72 + lg * 8];
    bf16x8 pa1 = *(const bf16x8*)&Plw[lr * 72 + 32 + lg * 8];
    bf16x8 ones;
    #pragma unroll
    for (int j = 0; j < 8; ++j) ones[j] = (bf16)1.0f;
    __builtin_amdgcn_s_setprio(1);
    lacc = mfma16(pa0, ones, lacc);
    lacc = mfma16(pa1, ones, lacc);
    #pragma unroll
    for (int df = 0; df < 4; ++df) {
        bf16x8 v0 = *(const bf16x8*)&Vl[(df * 16 + lr) * 64 + ((0 + lg) ^ (lr & 7)) * 8];
        bf16x8 v1 = *(const bf16x8*)&Vl[(df * 16 + lr) * 64 + ((4 + lg) ^ (lr & 7)) * 8];
        oacc[df] = mfma16(pa0, v0, oacc[df]);
        oacc[df] = mfma16(pa1, v1, oacc[df]);
    }
    __builtin_amdgcn_s_setprio(0);
}

__global__ __launch_bounds__(256)
void attn_fwd(const bf16* __restrict__ q, const bf16* __restrict__ k,
              const bf16* __restrict__ vt, bf16* __restrict__ o) {
    __shared__ bf16 Kl[2][64 * 64];
    __shared__ bf16 Vl[2][64 * 64];
    __shared__ bf16 Pl[4][16 * 72];
    const int tid = threadIdx.x, wid = tid >> 6, l = tid & 63;
    const int lr = l & 15, lg = l >> 4;
    const int qtA = blockIdx.x;           // 0..15
    const int qtB = 31 - qtA;             // 31..16
    const int bh = blockIdx.y;
    const long kbase = (long)bh * SEQ * HD;
    const long vbase = (long)bh * HD * SEQ;
    const int qwA = qtA * 64 + wid * 16;
    const int qwB = qtB * 64 + wid * 16;

    bf16x8 qA0, qA1, qB0, qB1;
    {
        const bf16* qp = q + kbase + (long)(qwA + lr) * HD + lg * 8;
        qA0 = *(const bf16x8*)qp; qA1 = *(const bf16x8*)(qp + 32);
        const bf16* qp2 = q + kbase + (long)(qwB + lr) * HD + lg * 8;
        qB0 = *(const bf16x8*)qp2; qB1 = *(const bf16x8*)(qp2 + 32);
    }
    f32x4 oA[4] = {}, oB[4] = {};
    f32x4 lA = {0.f, 0.f, 0.f, 0.f}, lB = {0.f, 0.f, 0.f, 0.f};
    float mA[4] = {-1e30f, -1e30f, -1e30f, -1e30f};
    float mB[4] = {-1e30f, -1e30f, -1e30f, -1e30f};

    auto stageKV = [&](int b, int tb) {
        #pragma unroll
        for (int i = 0; i < 4; ++i) {
            int slot = i * 256 + tid;
            int row = (slot >> 3) & 63;
            int bs = (slot & 7) ^ (row & 7);
            if (slot < 512)
                gload16(&k[kbase + (long)(tb + row) * HD + bs * 8], &Kl[b][slot * 8]);
            else
                gload16(&vt[vbase + (long)row * SEQ + tb + bs * 8], &Vl[b][(slot - 512) * 8]);
        }
    };

    const int nt = qtB + 1;
    stageKV(0, 0);
    __syncthreads();
    int cur = 0;
    for (int tb_i = 0; tb_i < nt; ++tb_i) {
        const int tb = tb_i * 64;
        if (tb_i + 1 < nt) stageKV(cur ^ 1, tb + 64);
        if (tb_i <= qtA)
            attn_tile(tb, qwA, tb_i == qtA, qA0, qA1, Kl[cur], Vl[cur], Pl[wid], lr, lg, oA, mA, lA);
        attn_tile(tb, qwB, tb_i == qtB, qB0, qB1, Kl[cur], Vl[cur], Pl[wid], lr, lg, oB, mB, lB);
        __syncthreads();
        cur ^= 1;
    }

    const int b = bh >> 4, h = bh & 15;
    #pragma unroll
    for (int df = 0; df < 4; ++df) {
        #pragma unroll
        for (int r = 0; r < 4; ++r) {
            int sA = qwA + 4 * lg + r;
            int sB = qwB + 4 * lg + r;
            o[((long)(b * SEQ + sA) * DM) + h * HD + df * 16 + lr] = (bf16)(oA[df][r] / lA[r]);
            o[((long)(b * SEQ + sB) * DM) + h * HD + df * 16 + lr] = (bf16)(oB[df][r] / lB[r]);
        }
    }
}

// ---------------- launch ----------------

extern "C" void kernel_launch(void* const* d_in, const int* in_sizes, int n_in,
                              void* d_out, int out_size, void* d_ws, size_t ws_size,
                              hipStream_t stream) {
    (void)in_sizes; (void)n_in; (void)out_size; (void)ws_size;
    const float* x    = (const float*)d_in[0];
    const float* rope = (const float*)d_in[1];
    const float* wq   = (const float*)d_in[2];
    const float* wk   = (const float*)d_in[3];
    const float* wv   = (const float*)d_in[4];
    const float* wo   = (const float*)d_in[5];
    const float* wg   = (const float*)d_in[6];
    const float* wu   = (const float*)d_in[7];
    const float* wd   = (const float*)d_in[8];
    const float* n1w  = (const float*)d_in[9];
    const float* n2w  = (const float*)d_in[10];
    float* out = (float*)d_out;

    char* ws = (char*)d_ws;
    const size_t MB = 1u << 20;
    bf16* wqkvb = (bf16*)(ws + 0 * MB);    // [3072][1024]  6 MB
    bf16* wob   = (bf16*)(ws + 6 * MB);    // [1024][1024]  2 MB
    bf16* wgub  = (bf16*)(ws + 8 * MB);    // [8192][1024] 16 MB (gate/up 32-interleave)
    bf16* wdb   = (bf16*)(ws + 24 * MB);   // [1024][4096]  8 MB
    bf16* hb    = (bf16*)(ws + 32 * MB);   //  8 MB
    bf16* qb_   = (bf16*)(ws + 40 * MB);   // 16 MB
    bf16* kb_   = (bf16*)(ws + 56 * MB);   // 16 MB
    bf16* vtb   = (bf16*)(ws + 72 * MB);   // 16 MB
    bf16* attnb = (bf16*)(ws + 88 * MB);   // 16 MB
    float* x2   = (float*)(ws + 40 * MB);  // 16 MB (aliases qb_, dead after attn)
    bf16* midb  = (bf16*)(ws + 56 * MB);   // 32 MB (aliases kb_+vtb, dead after attn)
    float* ctab = (float*)(ws + 104 * MB);
    float* stab = (float*)(ws + 104 * MB + (1u << 18));

    // all weights -> bf16 in one launch
    convert_all_k<<<8192, 256, 0, stream>>>(wq, wk, wv, wo, wg, wu, wd,
                                            wqkvb, wob, wgub, wdb);
    rope_table_k<<<256, 256, 0, stream>>>(rope, ctab, stab);

    // norm1 -> h
    rmsnorm_k<<<NROWS / 4, 256, 0, stream>>>(x, n1w, hb);

    // fused QKV (+RoPE on q/k, q pre-scaled, V transposed)
    gemm256<0><<<dim3(16, 12), 512, 0, stream>>>(hb, wqkvb, DM, qb_, kb_, vtb, ctab, stab);

    // attention
    attn_fwd<<<dim3(16, 32), 256, 0, stream>>>(qb_, kb_, vtb, attnb);

    // WO + residual -> x2 (f32)
    gemm64x128<<<dim3(64, 8), 512, 0, stream>>>(attnb, wob, DM, DM, x, x2);

    // norm2 -> h
    rmsnorm_k<<<NROWS / 4, 256, 0, stream>>>(x2, n2w, hb);

    // fused gate+up+silu -> midb
    gemm256<3><<<dim3(16, 32), 512, 0, stream>>>(hb, wgub, DM, midb, nullptr, nullptr, nullptr, nullptr);

    // down + residual -> out
    gemm64x128<<<dim3(64, 8), 512, 0, stream>>>(midb, wdb, DFF, DM, x2, out);
}